// Round 2
// baseline (416.280 us; speedup 1.0000x reference)
//
#include <hip/hip_runtime.h>
#include <hip/hip_bf16.h>

// GATv2Conv: N=100000, E=1000000, D_IN=128, D_OUT=64, D_EDGE=11
// heads=1, add_self_loops fill='mean', negative_slope=0.2
//
// R7: kill the 256-MB evec round trip. k_evec showed 190 MB writes at
// 1.5 TB/s random-128B (22% HBM, 14% VALU -> scatter-bound). The 64-d
// evec is only consumed as (a) scalar logit, (b) self-loop mean. So:
//   k_place2: gathers xl[src]/xr[dst] (L2/L3-resident 12.8 MB tables),
//     computes the FULL logit per edge, writes one 32-B CSR record
//     {src u32, logit f32, attr[11] bf16, pad} (was 128-B evec + 4-B srcs).
//   k_fused3: streams 32-B records (32 MB, was 132 MB), per edge just
//     exp(logit) + one cached xl gather; self-loop via streamed attr
//     (mean(attr)@We once per node).
// Predicted: k_place2 ~70us (WRITE ~50MB), k_fused3 ~55us, total ~250us.

#define NN 100000
#define EE 1000000
#define DI 128
#define DO 64
#define DE 11
#define NEG 0.2f
#define NGB 1563  // gemm blocks in k_gemm_deg; deg blocks follow

typedef __attribute__((ext_vector_type(8))) short short8;
typedef __attribute__((ext_vector_type(4))) float f32x4;

// ---- workspace layout (bytes) ----
#define XRB_B   ((size_t)0)            // NN*DO*2 bf16 xr
#define XLB_B   ((size_t)12800000)     // NN*DO*2 bf16 xl
#define REC_B   ((size_t)25600000)     // EE*32 records {src,logit,attr}
#define P_START ((size_t)57600000)
#define P_CUR   ((size_t)58000000)
#define P_DEG   ((size_t)58400000)
#define P_CNT   ((size_t)58800000)     // covered by deg memset (NN+1)

__device__ inline float4 bf4_to_f4(uint2 r) {
  float4 f;
  f.x = __uint_as_float(r.x << 16);
  f.y = __uint_as_float(r.x & 0xFFFF0000u);
  f.z = __uint_as_float(r.y << 16);
  f.w = __uint_as_float(r.y & 0xFFFF0000u);
  return f;
}

__device__ inline float bfu_to_f(unsigned short u) {
  return __uint_as_float(((unsigned)u) << 16);
}

__device__ inline short f2bfs(float v) {
  union { __hip_bfloat16 b; short s; } u;
  u.b = __float2bfloat16(v);
  return u.s;
}

__device__ inline unsigned pk2(float a, float b) {
  return ((unsigned)(unsigned short)f2bfs(a)) |
         (((unsigned)(unsigned short)f2bfs(b)) << 16);
}

// ---- fused GEMM (blocks [0,NGB)) + degree count (blocks [NGB,..)) ----
__global__ __launch_bounds__(256) void k_gemm_deg(
    const float* __restrict__ x, const float* __restrict__ Wl,
    const float* __restrict__ Wr, const int* __restrict__ ei,
    unsigned short* __restrict__ xlb, unsigned short* __restrict__ xrb,
    unsigned* __restrict__ deg) {
  __shared__ short wldsL[8192];
  __shared__ short wldsR[8192];
  if (blockIdx.x >= NGB) {  // degree-count blocks
    int e = (blockIdx.x - NGB) * 256 + threadIdx.x;
    if (e < EE) atomicAdd(&deg[ei[EE + e]], 1u);
    return;
  }
  // B fragments pre-swizzled: [ks][nb][quad][l16][j] shorts
  for (int t = threadIdx.x; t < 8192; t += 256) {
    int k = t >> 6, n = t & 63;
    int off = ((((k >> 5) * 4 + (n >> 4)) * 4 + ((k >> 3) & 3)) * 16 + (n & 15)) * 8 + (k & 7);
    wldsL[off] = f2bfs(Wl[t]);
    wldsR[off] = f2bfs(Wr[t]);
  }
  __syncthreads();

  int wave = threadIdx.x >> 6;
  int lane = threadIdx.x & 63;
  int quad = lane >> 4;
  int l16 = lane & 15;
  int m0 = (blockIdx.x * 4 + wave) * 16;
  int row = m0 + l16;
  bool rowok = row < NN;

  f32x4 accL[4], accR[4];
#pragma unroll
  for (int nb = 0; nb < 4; ++nb) {
    accL[nb] = (f32x4){0.f, 0.f, 0.f, 0.f};
    accR[nb] = (f32x4){0.f, 0.f, 0.f, 0.f};
  }
#pragma unroll
  for (int ks = 0; ks < 4; ++ks) {
    short8 a;
    if (rowok) {
      const float* xp = x + (size_t)row * DI + ks * 32 + quad * 8;
      float4 v0 = *(const float4*)xp;
      float4 v1 = *(const float4*)(xp + 4);
      a[0] = f2bfs(v0.x); a[1] = f2bfs(v0.y); a[2] = f2bfs(v0.z); a[3] = f2bfs(v0.w);
      a[4] = f2bfs(v1.x); a[5] = f2bfs(v1.y); a[6] = f2bfs(v1.z); a[7] = f2bfs(v1.w);
    } else {
#pragma unroll
      for (int j = 0; j < 8; ++j) a[j] = 0;
    }
#pragma unroll
    for (int nb = 0; nb < 4; ++nb) {
      int off = (((ks * 4 + nb) * 4 + quad) * 16 + l16) * 8;
      short8 bl = *(const short8*)(wldsL + off);
      short8 br = *(const short8*)(wldsR + off);
      accL[nb] = __builtin_amdgcn_mfma_f32_16x16x32_bf16(a, bl, accL[nb], 0, 0, 0);
      accR[nb] = __builtin_amdgcn_mfma_f32_16x16x32_bf16(a, br, accR[nb], 0, 0, 0);
    }
  }
  // D layout: row = quad*4 + reg, col = l16 (m89-verified)
#pragma unroll
  for (int reg = 0; reg < 4; ++reg) {
    int r = m0 + quad * 4 + reg;
    if (r < NN) {
      size_t base = (size_t)r * DO + l16;
#pragma unroll
      for (int nb = 0; nb < 4; ++nb) {
        xlb[base + nb * 16] = (unsigned short)f2bfs(accL[nb][reg]);
        xrb[base + nb * 16] = (unsigned short)f2bfs(accR[nb][reg]);
      }
    }
  }
}

__global__ __launch_bounds__(256) void k_scan(const unsigned* __restrict__ deg,
                                              unsigned* __restrict__ start,
                                              unsigned* __restrict__ cursor,
                                              unsigned* __restrict__ counter) {
  int i = blockIdx.x * 256 + threadIdx.x;
  int lane = threadIdx.x & 63;
  unsigned d = (i < NN) ? deg[i] : 0u;
  unsigned incl = d;
#pragma unroll
  for (int sh = 1; sh < 64; sh <<= 1) {
    unsigned v = __shfl_up(incl, sh, 64);
    if (lane >= sh) incl += v;
  }
  unsigned total = __shfl(incl, 63, 64);
  unsigned base = 0;
  if (lane == 63) base = atomicAdd(counter, total);
  base = __shfl(base, 63, 64);
  unsigned s = base + incl - d;
  if (i < NN) { start[i] = s; cursor[i] = s; }
}

// ---- placement + FULL logit per edge; 32-B CSR record ----
// record (32 B = 8 u32 = 16 u16): [0]=src, [1]=logit f32,
// shorts[4..14]=attr[0..10] bf16, short[15]=pad
__global__ __launch_bounds__(256) void k_place2(
    const int* __restrict__ ei, const float* __restrict__ attr,
    const float* __restrict__ We, const float* __restrict__ att,
    const unsigned short* __restrict__ xlb, const unsigned short* __restrict__ xrb,
    unsigned* __restrict__ cursor, unsigned* __restrict__ rec) {
  int g = threadIdx.x & 15;
  int k0 = g * 4;
  int grp = (blockIdx.x * 256 + threadIdx.x) >> 4;
  int gstride = (gridDim.x * 256) >> 4;
  float4 W[DE];
#pragma unroll
  for (int j = 0; j < DE; ++j) W[j] = *(const float4*)(We + j * DO + k0);
  const float4 a4 = *(const float4*)(att + k0);
  for (int e = grp; e < EE; e += gstride) {
    unsigned src = (unsigned)ei[e];
    unsigned dst = (unsigned)ei[EE + e];
    const float* ar = attr + (size_t)e * DE;  // same addr across 16 lanes
    float av[DE];
#pragma unroll
    for (int j = 0; j < DE; ++j) av[j] = ar[j];
    // gathers from L2/L3-resident bf16 tables (12.8 MB each)
    float4 vl = bf4_to_f4(*(const uint2*)(xlb + (size_t)src * DO + k0));
    float4 vr = bf4_to_f4(*(const uint2*)(xrb + (size_t)dst * DO + k0));
    float4 m;
    m.x = vl.x + vr.x; m.y = vl.y + vr.y;
    m.z = vl.z + vr.z; m.w = vl.w + vr.w;
#pragma unroll
    for (int j = 0; j < DE; ++j) {
      m.x += av[j] * W[j].x; m.y += av[j] * W[j].y;
      m.z += av[j] * W[j].z; m.w += av[j] * W[j].w;
    }
    m.x = m.x >= 0.f ? m.x : NEG * m.x;
    m.y = m.y >= 0.f ? m.y : NEG * m.y;
    m.z = m.z >= 0.f ? m.z : NEG * m.z;
    m.w = m.w >= 0.f ? m.w : NEG * m.w;
    float s = m.x * a4.x + m.y * a4.y + m.z * a4.z + m.w * a4.w;
    s += __shfl_xor(s, 1); s += __shfl_xor(s, 2);
    s += __shfl_xor(s, 4); s += __shfl_xor(s, 8);
    unsigned pos;
    if (g == 0) pos = atomicAdd(&cursor[dst], 1u);
    pos = __shfl(pos, 0, 16);
    uint2 w;
    if (g == 0)      { w.x = src;               w.y = __float_as_uint(s); }
    else if (g == 1) { w.x = pk2(av[0], av[1]); w.y = pk2(av[2], av[3]); }
    else if (g == 2) { w.x = pk2(av[4], av[5]); w.y = pk2(av[6], av[7]); }
    else             { w.x = pk2(av[8], av[9]);
                       w.y = (unsigned)(unsigned short)f2bfs(av[10]); }
    if (g < 4) *(uint2*)(rec + (size_t)pos * 8 + g * 2) = w;
  }
}

// ---- final pass: stream 32-B records, exp + gather + accumulate ----
__global__ __launch_bounds__(128) void k_fused3(
    const unsigned short* __restrict__ xlb, const unsigned short* __restrict__ xrb,
    const unsigned* __restrict__ rec, const float* __restrict__ We,
    const float* __restrict__ att, const unsigned* __restrict__ start,
    const unsigned* __restrict__ deg, float* __restrict__ out) {
  int t = blockIdx.x * 128 + threadIdx.x;
  int i = t >> 4;  // 16 lanes per dst node, 4 dims per lane
  int g = t & 15;
  if (i >= NN) return;
  unsigned s0 = start[i];
  unsigned d = deg[i];
  int k0 = g * 4;

  const float4 a4 = *(const float4*)(att + k0);
  float4 xri = bf4_to_f4(*(const uint2*)(xrb + (size_t)i * DO + k0));
  float4 xli = bf4_to_f4(*(const uint2*)(xlb + (size_t)i * DO + k0));
  const unsigned short* recs = (const unsigned short*)rec;

  float4 acc = {0.f, 0.f, 0.f, 0.f};
  float den = 0.f;
  float asum = 0.f;  // lane g (g<11) accumulates attr[g] over incoming edges

  for (unsigned c = 0; c < d; c += 8) {
    unsigned rem = d - c;
    if (rem > 8) rem = 8;
    size_t sp = s0 + c;
    // (1) headers {src, logit} — same addr across 16 lanes, sequential stream
#define LH(ii)                                                              \
    uint2 H##ii = {0u, 0u};                                                 \
    if ((unsigned)ii < rem) H##ii = *(const uint2*)(rec + (sp + ii) * 8);
    LH(0) LH(1) LH(2) LH(3) LH(4) LH(5) LH(6) LH(7)
#undef LH
    // (2) this lane's attr piece (L1-hot line just streamed)
#define LA(ii)                                                              \
    float A##ii = 0.f;                                                      \
    if ((unsigned)ii < rem && g < DE)                                       \
      A##ii = bfu_to_f(recs[(sp + ii) * 16 + 4 + g]);
    LA(0) LA(1) LA(2) LA(3) LA(4) LA(5) LA(6) LA(7)
#undef LA
    // (3) xl gathers (cache-resident table, 8 in flight)
#define LR(ii)                                                              \
    uint2 R##ii = {0u, 0u};                                                 \
    if ((unsigned)ii < rem) R##ii = *(const uint2*)(xlb + (size_t)H##ii.x * DO + k0);
    LR(0) LR(1) LR(2) LR(3) LR(4) LR(5) LR(6) LR(7)
#undef LR
    // (4) consume: exp(logit) + weighted accumulate
#define CS(ii)                                                              \
    if ((unsigned)ii < rem) {                                               \
      float4 vl = bf4_to_f4(R##ii);                                         \
      float ex = __expf(__uint_as_float(H##ii.y));                          \
      acc.x += ex * vl.x; acc.y += ex * vl.y;                               \
      acc.z += ex * vl.z; acc.w += ex * vl.w;                               \
      den += ex;                                                            \
      asum += A##ii;                                                        \
    }
    CS(0) CS(1) CS(2) CS(3) CS(4) CS(5) CS(6) CS(7)
#undef CS
  }

  // self-loop: mean(attr)@We (linearity), computed once per node
  float invd = 1.0f / fmaxf((float)d, 1.0f);
  float4 evs = {0.f, 0.f, 0.f, 0.f};
#pragma unroll
  for (int j = 0; j < DE; ++j) {
    float aj = __shfl(asum, j, 16) * invd;
    float4 w = *(const float4*)(We + j * DO + k0);
    evs.x += aj * w.x; evs.y += aj * w.y;
    evs.z += aj * w.z; evs.w += aj * w.w;
  }
  float4 m;
  m.x = xli.x + xri.x + evs.x;
  m.y = xli.y + xri.y + evs.y;
  m.z = xli.z + xri.z + evs.z;
  m.w = xli.w + xri.w + evs.w;
  m.x = m.x >= 0.f ? m.x : NEG * m.x;
  m.y = m.y >= 0.f ? m.y : NEG * m.y;
  m.z = m.z >= 0.f ? m.z : NEG * m.z;
  m.w = m.w >= 0.f ? m.w : NEG * m.w;
  float s = m.x * a4.x + m.y * a4.y + m.z * a4.z + m.w * a4.w;
  s += __shfl_xor(s, 1); s += __shfl_xor(s, 2);
  s += __shfl_xor(s, 4); s += __shfl_xor(s, 8);
  float exs = __expf(s);
  float inv = 1.0f / (den + exs);
  float4 o;
  o.x = (acc.x + exs * xli.x) * inv;
  o.y = (acc.y + exs * xli.y) * inv;
  o.z = (acc.z + exs * xli.z) * inv;
  o.w = (acc.w + exs * xli.w) * inv;
  *(float4*)(out + (size_t)i * DO + k0) = o;
}

extern "C" void kernel_launch(void* const* d_in, const int* in_sizes, int n_in,
                              void* d_out, int out_size, void* d_ws, size_t ws_size,
                              hipStream_t stream) {
  const float* x    = (const float*)d_in[0];
  const int*   ei   = (const int*)d_in[1];
  const float* attr = (const float*)d_in[2];
  const float* Wl   = (const float*)d_in[3];
  const float* Wr   = (const float*)d_in[4];
  const float* We   = (const float*)d_in[5];
  const float* att  = (const float*)d_in[6];
  float* out = (float*)d_out;

  char* ws = (char*)d_ws;
  unsigned short* xrb  = (unsigned short*)(ws + XRB_B);
  unsigned short* xlb  = (unsigned short*)(ws + XLB_B);
  unsigned*       rec  = (unsigned*)(ws + REC_B);
  unsigned* start   = (unsigned*)(ws + P_START);
  unsigned* cursor  = (unsigned*)(ws + P_CUR);
  unsigned* deg     = (unsigned*)(ws + P_DEG);
  unsigned* counter = (unsigned*)(ws + P_CNT);

  hipMemsetAsync(deg, 0, (size_t)(NN + 1) * sizeof(unsigned), stream);

  k_gemm_deg<<<NGB + (EE + 255) / 256, 256, 0, stream>>>(x, Wl, Wr, ei,
                                                         xlb, xrb, deg);
  k_scan<<<(NN + 255) / 256, 256, 0, stream>>>(deg, start, cursor, counter);
  k_place2<<<7813, 256, 0, stream>>>(ei, attr, We, att, xlb, xrb, cursor, rec);
  k_fused3<<<(NN * 16) / 128, 128, 0, stream>>>(xlb, xrb, rec, We, att,
                                                start, deg, out);
}